// Round 7
// baseline (301.711 us; speedup 1.0000x reference)
//
#include <hip/hip_runtime.h>
#include <stdint.h>

#define BB 32
#define SS 512
#define HH 256
#define MM (BB*SS)     // 16384 rows
#define MAXMEL 2048

typedef _Float16 f16;
typedef _Float16 f16x4 __attribute__((ext_vector_type(4)));
typedef _Float16 f16x8 __attribute__((ext_vector_type(8)));
typedef float    f32x16 __attribute__((ext_vector_type(16)));

// Xg layout: [cb 16][row MM][16 chans] (32B per row per 16-chan panel)
__device__ __forceinline__ size_t xoff(int row, int chan) {
  return ((size_t)(chan >> 4) * MM + row) * 16 + (chan & 15);
}

#define WSZP ((size_t)393216)   // packed weight elems per conv (both planes)

// ---------------- conv1d (K=3 SAME, 256->256), split-f16 MFMA, LDS-FREE ------
// Block 128x128, 4 waves (2x2), wave tile 64x64 (2m x 2n frags of 32x32x16).
// 16 steps of 16 chans x 3 taps. All operands direct global->reg, fully
// coalesced via Xg layout / packed weights; L2-resident slices. 3-product
// split: Ahi*Bhi + Ahi*Blo + Alo*Bhi (~f32 accuracy). No LDS, no barriers.
__global__ __launch_bounds__(256) void convA(
    const f16* __restrict__ X0h, const f16* __restrict__ X0l,
    const f16* __restrict__ X1h_, const f16* __restrict__ X1l_,
    const f16* __restrict__ W0,  const f16* __restrict__ W1,   // packed
    const float* __restrict__ bias0, const float* __restrict__ bias1,
    f16* __restrict__ Y0h, f16* __restrict__ Y0l,
    f16* __restrict__ Y1h, f16* __restrict__ Y1l)
{
  const int tid = threadIdx.x;
  const int lane = tid & 63, wid = tid >> 6;
  const int bm = blockIdx.x, bn = blockIdx.y, bz = blockIdx.z;
  const int l31 = lane & 31, half = lane >> 5;
  const int wr = wid >> 1, wc = wid & 1;

  const f16* Xh = bz ? X1h_ : X0h;
  const f16* Xl = bz ? X1l_ : X0l;
  const f16* Wp = bz ? W1 : W0;

  // ---- A pointers: per (mi, tap, p); lane -> row, half -> k-group ----
  const f16* aptr[2][3][2];
  bool vld[2][3];
  #pragma unroll
  for (int mi = 0; mi < 2; ++mi)
    #pragma unroll
    for (int tap = 0; tap < 3; ++tap) {
      int row_l = wr * 64 + mi * 32 + l31;
      int sseq  = (bm & 3) * 128 + row_l + tap - 1;
      vld[mi][tap] = ((unsigned)sseq < 512u);
      int rowg = bm * 128 + row_l + tap - 1;
      rowg = rowg < 0 ? 0 : (rowg >= MM ? MM - 1 : rowg);
      size_t o = (size_t)rowg * 16 + half * 8;
      aptr[mi][tap][0] = Xh + o;
      aptr[mi][tap][1] = Xl + o;
    }

  // ---- B pointers: per (tap, p, n); lane -> col, half -> k-group ----
  // packed: [bn2][s16][p2][tap3][col128][g2][8]
  const f16* bptr[3][2][2];
  #pragma unroll
  for (int tap = 0; tap < 3; ++tap)
    #pragma unroll
    for (int p = 0; p < 2; ++p)
      #pragma unroll
      for (int n = 0; n < 2; ++n) {
        int col = wc * 64 + n * 32 + l31;
        size_t u = ((((size_t)(bn * 16) * 2 + p) * 3 + tap) * 128 + col) * 16
                   + half * 8;
        bptr[tap][p][n] = Wp + u;
      }

  f32x16 acc[2][2];
  #pragma unroll
  for (int mi = 0; mi < 2; ++mi)
    #pragma unroll
    for (int ni = 0; ni < 2; ++ni) acc[mi][ni] = (f32x16)0.f;

  const size_t astr = (size_t)MM * 16;     // elems per step (A)
  const size_t bstr = (size_t)12288;       // elems per step (B)

  #pragma unroll
  for (int t = 0; t < 16; ++t) {
    f16x8 av[2][3][2];
    #pragma unroll
    for (int mi = 0; mi < 2; ++mi)
      #pragma unroll
      for (int tap = 0; tap < 3; ++tap)
        #pragma unroll
        for (int p = 0; p < 2; ++p)
          av[mi][tap][p] = *(const f16x8*)(aptr[mi][tap][p] + (size_t)t * astr);
    // zero invalid boundary rows (cross-sequence / OOB taps)
    if (!vld[0][0]) { av[0][0][0] = (f16x8)(f16)0.f; av[0][0][1] = (f16x8)(f16)0.f; }
    if (!vld[1][2]) { av[1][2][0] = (f16x8)(f16)0.f; av[1][2][1] = (f16x8)(f16)0.f; }

    f16x8 bv[3][2][2];
    #pragma unroll
    for (int tap = 0; tap < 3; ++tap)
      #pragma unroll
      for (int p = 0; p < 2; ++p)
        #pragma unroll
        for (int n = 0; n < 2; ++n)
          bv[tap][p][n] = *(const f16x8*)(bptr[tap][p][n] + (size_t)t * bstr);

    #pragma unroll
    for (int tap = 0; tap < 3; ++tap)
      #pragma unroll
      for (int mi = 0; mi < 2; ++mi)
        #pragma unroll
        for (int ni = 0; ni < 2; ++ni) {
          acc[mi][ni] = __builtin_amdgcn_mfma_f32_32x32x16_f16(av[mi][tap][0], bv[tap][0][ni], acc[mi][ni], 0, 0, 0);
          acc[mi][ni] = __builtin_amdgcn_mfma_f32_32x32x16_f16(av[mi][tap][0], bv[tap][1][ni], acc[mi][ni], 0, 0, 0);
          acc[mi][ni] = __builtin_amdgcn_mfma_f32_32x32x16_f16(av[mi][tap][1], bv[tap][0][ni], acc[mi][ni], 0, 0, 0);
        }
  }

  // epilogue: +bias, ReLU, split, store planes in Xg layout.
  // C/D layout: col=lane&31, row=(reg&3)+8*(reg>>2)+4*(lane>>5)
  const float* bias = bz ? bias1 : bias0;
  f16* Yh = bz ? Y1h : Y0h;
  f16* Yl = bz ? Y1l : Y0l;
  #pragma unroll
  for (int mi = 0; mi < 2; ++mi)
    #pragma unroll
    for (int ni = 0; ni < 2; ++ni) {
      int colg = bn * 128 + wc * 64 + ni * 32 + l31;
      float bvs = bias[colg];
      size_t cbase = (size_t)(colg >> 4) * MM * 16 + (colg & 15);
      #pragma unroll
      for (int r = 0; r < 16; ++r) {
        int rowl = (r & 3) + 8 * (r >> 2) + 4 * half;
        int rowg = bm * 128 + wr * 64 + mi * 32 + rowl;
        float v = fmaxf(acc[mi][ni][r] + bvs, 0.f);
        f16 h = (f16)v;
        f16 l = (f16)(v - (float)h);
        size_t o = cbase + (size_t)rowg * 16;
        Yh[o] = h;
        Yl[o] = l;
      }
    }
}

// ---------------- weight pack+split, all 6 weights in one launch ----------------
// packed per conv: [bn2][s16][p2][tap3][col128][g2][8 f16]; p0=hi, p1=lo
__global__ __launch_bounds__(256) void wsplit6(
    const float* __restrict__ W0, const float* __restrict__ W1,
    const float* __restrict__ W2, const float* __restrict__ W3,
    const float* __restrict__ W4, const float* __restrict__ W5,
    f16* __restrict__ Wt)
{
  int z = blockIdx.y;
  const float* W = z==0?W0 : z==1?W1 : z==2?W2 : z==3?W3 : z==4?W4 : W5;
  f16* T = Wt + (size_t)z * WSZP;
  int id = blockIdx.x * 256 + threadIdx.x;    // [0, 49152) 16B units
  int g = id & 1;
  int t1 = id >> 1;
  int col = t1 & 127;
  int t2 = t1 >> 7;
  int tap = t2 % 3;
  int t3 = t2 / 3;
  int p = t3 & 1;
  int t4 = t3 >> 1;
  int s = t4 & 15;
  int bn = t4 >> 4;
  int chan = s * 16 + g * 8;
  int colg = bn * 128 + col;
  f16x8 o;
  #pragma unroll
  for (int e = 0; e < 8; ++e) {
    float w = W[(size_t)(tap * 256 + chan + e) * 256 + colg];
    f16 h = (f16)w;
    o[e] = p ? (f16)(w - (float)h) : h;
  }
  *(f16x8*)(T + (size_t)id * 8) = o;
}

// ---------------- split f32 -> hi/lo planes (Xg layout) ----------------
__global__ __launch_bounds__(256) void split2(
    const float* __restrict__ X, f16* __restrict__ Hi, f16* __restrict__ Lo)
{
  int id = blockIdx.x * 256 + threadIdx.x;    // [0, MM*32)
  int row = id >> 5, chan = (id & 31) * 8;
  const float* src = X + (size_t)row * 256 + chan;
  float4 v0 = *(const float4*)src;
  float4 v1 = *(const float4*)(src + 4);
  float vv[8] = {v0.x, v0.y, v0.z, v0.w, v1.x, v1.y, v1.z, v1.w};
  f16x8 h, l;
  #pragma unroll
  for (int j = 0; j < 8; ++j) {
    f16 hh = (f16)vv[j];
    h[j] = hh;
    l[j] = (f16)(vv[j] - (float)hh);
  }
  size_t o = xoff(row, chan);
  *(f16x8*)(Hi + o) = h;
  *(f16x8*)(Lo + o) = l;
}

// ---------------- fused LN (z picks predictor set) ----------------
__global__ __launch_bounds__(256) void lnF(
    f16* __restrict__ P0h, f16* __restrict__ P0l,
    f16* __restrict__ P1h, f16* __restrict__ P1l,
    const float* __restrict__ g0, const float* __restrict__ be0,
    const float* __restrict__ g1, const float* __restrict__ be1)
{
  int z = blockIdx.y;
  f16* Ph = z ? P1h : P0h;
  f16* Pl = z ? P1l : P0l;
  const float* g  = z ? g1 : g0;
  const float* be = z ? be1 : be0;
  int row  = blockIdx.x * 4 + (threadIdx.x >> 6);
  int lane = threadIdx.x & 63;
  size_t o = xoff(row, lane * 4);
  f16x4 h = *(const f16x4*)(Ph + o);
  f16x4 l = *(const f16x4*)(Pl + o);
  float v[4];
  #pragma unroll
  for (int j = 0; j < 4; ++j) v[j] = (float)h[j] + (float)l[j];
  float s = v[0] + v[1] + v[2] + v[3];
  float q = v[0]*v[0] + v[1]*v[1] + v[2]*v[2] + v[3]*v[3];
  #pragma unroll
  for (int d = 32; d > 0; d >>= 1) { s += __shfl_xor(s, d); q += __shfl_xor(q, d); }
  float mean = s * (1.f / 256.f);
  float var  = q * (1.f / 256.f) - mean * mean;
  float inv  = 1.0f / sqrtf(var + 1e-5f);
  float4 gg = *(const float4*)(g + lane * 4);
  float4 bb = *(const float4*)(be + lane * 4);
  float gv[4] = {gg.x, gg.y, gg.z, gg.w};
  float bv[4] = {bb.x, bb.y, bb.z, bb.w};
  #pragma unroll
  for (int j = 0; j < 4; ++j) {
    float oo = (v[j] - mean) * inv * gv[j] + bv[j];
    f16 hh = (f16)oo;
    h[j] = hh;
    l[j] = (f16)(oo - (float)hh);
  }
  *(f16x4*)(Ph + o) = h;
  *(f16x4*)(Pl + o) = l;
}

// ------- fused LN+head for dur (z=0) and pit (z=1, + bucket + emb add) -------
__global__ __launch_bounds__(256) void lnheadD(
    const f16* __restrict__ U0h, const f16* __restrict__ U0l,
    const f16* __restrict__ U1h, const f16* __restrict__ U1l,
    const float* __restrict__ g0, const float* __restrict__ be0,
    const float* __restrict__ wl0, const float* __restrict__ bl0,
    const float* __restrict__ g1, const float* __restrict__ be1,
    const float* __restrict__ wl1, const float* __restrict__ bl1,
    const unsigned char* __restrict__ mask, const float* __restrict__ pc,
    float* __restrict__ o_ldur, float* __restrict__ pred_d,
    float* __restrict__ o_pit,
    const float* __restrict__ pbins, const float* __restrict__ pemb,
    const f16* __restrict__ XPh, const f16* __restrict__ XPl,
    f16* __restrict__ X1h, f16* __restrict__ X1l)
{
  int z = blockIdx.y;
  int row  = blockIdx.x * 4 + (threadIdx.x >> 6);
  int lane = threadIdx.x & 63;
  size_t o = xoff(row, lane * 4);
  const f16* Uh = z ? U1h : U0h;
  const f16* Ul = z ? U1l : U0l;
  f16x4 h = *(const f16x4*)(Uh + o);
  f16x4 l = *(const f16x4*)(Ul + o);
  float v[4];
  #pragma unroll
  for (int j = 0; j < 4; ++j) v[j] = (float)h[j] + (float)l[j];
  float s = v[0] + v[1] + v[2] + v[3];
  float q = v[0]*v[0] + v[1]*v[1] + v[2]*v[2] + v[3]*v[3];
  #pragma unroll
  for (int d = 32; d > 0; d >>= 1) { s += __shfl_xor(s, d); q += __shfl_xor(q, d); }
  float mean = s * (1.f / 256.f);
  float var  = q * (1.f / 256.f) - mean * mean;
  float inv  = 1.0f / sqrtf(var + 1e-5f);
  const float* g  = z ? g1  : g0;
  const float* be = z ? be1 : be0;
  const float* wl = z ? wl1 : wl0;
  float4 gg = *(const float4*)(g + lane * 4);
  float4 bb = *(const float4*)(be + lane * 4);
  float4 ww = *(const float4*)(wl + lane * 4);
  float gv[4] = {gg.x, gg.y, gg.z, gg.w};
  float bv[4] = {bb.x, bb.y, bb.z, bb.w};
  float wv[4] = {ww.x, ww.y, ww.z, ww.w};
  float acc = 0.f;
  #pragma unroll
  for (int j = 0; j < 4; ++j)
    acc += ((v[j] - mean) * inv * gv[j] + bv[j]) * wv[j];
  #pragma unroll
  for (int d = 32; d > 0; d >>= 1) acc += __shfl_xor(acc, d);
  float r = acc + (z ? bl1 : bl0)[0];
  if (mask[row]) r = 0.f;
  if (z == 0) {
    if (lane == 0) { o_ldur[row] = r; pred_d[row] = r; }
  } else {
    r *= pc[0];
    if (lane == 0) o_pit[row] = r;
    int lo = 0, hi = 255;
    while (lo < hi) { int mid = (lo + hi) >> 1; if (pbins[mid] < r) lo = mid + 1; else hi = mid; }
    f16x4 xh = *(const f16x4*)(XPh + o);
    f16x4 xl = *(const f16x4*)(XPl + o);
    float4 e = *(const float4*)(pemb + (size_t)lo * HH + lane * 4);
    float ev[4] = {e.x, e.y, e.z, e.w};
    #pragma unroll
    for (int j = 0; j < 4; ++j) {
      float oo = (float)xh[j] + (float)xl[j] + ev[j];
      f16 hh = (f16)oo;
      xh[j] = hh;
      xl[j] = (f16)(oo - (float)hh);
    }
    *(f16x4*)(X1h + o) = xh;
    *(f16x4*)(X1l + o) = xl;
  }
}

// ------- energy final: LN + head + bucket + emb add -------
__global__ __launch_bounds__(256) void lnheadE(
    const f16* __restrict__ Uh, const f16* __restrict__ Ul,
    const float* __restrict__ g, const float* __restrict__ be,
    const float* __restrict__ wl, const float* __restrict__ bl,
    const unsigned char* __restrict__ mask, const float* __restrict__ ec,
    float* __restrict__ o_ene,
    const float* __restrict__ ebins, const float* __restrict__ eemb,
    const f16* __restrict__ X1h, const f16* __restrict__ X1l,
    f16* __restrict__ X2h, f16* __restrict__ X2l)
{
  int row  = blockIdx.x * 4 + (threadIdx.x >> 6);
  int lane = threadIdx.x & 63;
  size_t o = xoff(row, lane * 4);
  f16x4 h = *(const f16x4*)(Uh + o);
  f16x4 l = *(const f16x4*)(Ul + o);
  float v[4];
  #pragma unroll
  for (int j = 0; j < 4; ++j) v[j] = (float)h[j] + (float)l[j];
  float s = v[0] + v[1] + v[2] + v[3];
  float q = v[0]*v[0] + v[1]*v[1] + v[2]*v[2] + v[3]*v[3];
  #pragma unroll
  for (int d = 32; d > 0; d >>= 1) { s += __shfl_xor(s, d); q += __shfl_xor(q, d); }
  float mean = s * (1.f / 256.f);
  float var  = q * (1.f / 256.f) - mean * mean;
  float inv  = 1.0f / sqrtf(var + 1e-5f);
  float4 gg = *(const float4*)(g + lane * 4);
  float4 bb = *(const float4*)(be + lane * 4);
  float4 ww = *(const float4*)(wl + lane * 4);
  float gv[4] = {gg.x, gg.y, gg.z, gg.w};
  float bv[4] = {bb.x, bb.y, bb.z, bb.w};
  float wv[4] = {ww.x, ww.y, ww.z, ww.w};
  float acc = 0.f;
  #pragma unroll
  for (int j = 0; j < 4; ++j)
    acc += ((v[j] - mean) * inv * gv[j] + bv[j]) * wv[j];
  #pragma unroll
  for (int d = 32; d > 0; d >>= 1) acc += __shfl_xor(acc, d);
  float r = acc + bl[0];
  if (mask[row]) r = 0.f;
  r *= ec[0];
  if (lane == 0) o_ene[row] = r;
  int lo = 0, hi = 255;
  while (lo < hi) { int mid = (lo + hi) >> 1; if (ebins[mid] < r) lo = mid + 1; else hi = mid; }
  f16x4 xh = *(const f16x4*)(X1h + o);
  f16x4 xl = *(const f16x4*)(X1l + o);
  float4 e = *(const float4*)(eemb + (size_t)lo * HH + lane * 4);
  float ev[4] = {e.x, e.y, e.z, e.w};
  #pragma unroll
  for (int j = 0; j < 4; ++j) {
    float oo = (float)xh[j] + (float)xl[j] + ev[j];
    f16 hh = (f16)oo;
    xh[j] = hh;
    xl[j] = (f16)(oo - (float)hh);
  }
  *(f16x4*)(X2h + o) = xh;
  *(f16x4*)(X2l + o) = xl;
}

// ---------------- duration post: dur, cumsum, mel_len ----------------
__global__ __launch_bounds__(512) void dur_post(
    const float* __restrict__ logdur, const float* __restrict__ dc,
    float* __restrict__ out_dur, float* __restrict__ out_mel_len,
    int* __restrict__ cum_ws, int* __restrict__ mel_len_ws)
{
  __shared__ int wsum[8];
  int b = blockIdx.x, t = threadIdx.x;
  float ld = logdur[b * SS + t];
  float d  = fmaxf(rintf(expf(ld) - 1.f) * dc[0], 0.f);
  out_dur[b * SS + t] = d;
  int di = (int)d;
  int lane = t & 63, w = t >> 6;
  int x = di;
  #pragma unroll
  for (int dd = 1; dd < 64; dd <<= 1) {
    int n = __shfl_up(x, dd);
    if (lane >= dd) x += n;
  }
  if (lane == 63) wsum[w] = x;
  __syncthreads();
  int off = 0;
  for (int i = 0; i < w; ++i) off += wsum[i];
  x += off;
  cum_ws[b * SS + t] = x;
  if (t == SS - 1) {
    int ml = min(x, MAXMEL);
    mel_len_ws[b] = ml;
    out_mel_len[b] = (float)ml;
  }
}

// ---------------- length regulator from Xg planes ----------------
__global__ __launch_bounds__(256) void gather_planes(
    const f16* __restrict__ Xhi, const f16* __restrict__ Xlo,
    const int* __restrict__ cum, const int* __restrict__ mel_len_ws,
    float* __restrict__ out_x, float* __restrict__ out_mask)
{
  __shared__ int c[SS];
  int b   = blockIdx.y;
  int tid = threadIdx.x;
  c[tid]       = cum[b * SS + tid];
  c[tid + 256] = cum[b * SS + tid + 256];
  __syncthreads();
  int w = tid >> 6, lane = tid & 63;
  int t = blockIdx.x * 4 + w;
  int lo = 0, hi = SS;
  while (lo < hi) { int mid = (lo + hi) >> 1; if (c[mid] <= t) lo = mid + 1; else hi = mid; }
  int idx = min(lo, SS - 1);
  int ml  = mel_len_ws[b];
  bool m  = (t >= ml);
  float4 v = make_float4(0.f, 0.f, 0.f, 0.f);
  if (!m) {
    size_t o = xoff(b * SS + idx, lane * 4);
    f16x4 xh = *(const f16x4*)(Xhi + o);
    f16x4 xl = *(const f16x4*)(Xlo + o);
    v.x = (float)xh[0] + (float)xl[0];
    v.y = (float)xh[1] + (float)xl[1];
    v.z = (float)xh[2] + (float)xl[2];
    v.w = (float)xh[3] + (float)xl[3];
  }
  *(float4*)(out_x + ((size_t)b * MAXMEL + t) * HH + lane * 4) = v;
  if (lane == 0) out_mask[b * MAXMEL + t] = m ? 1.f : 0.f;
}

// ---------------- launcher ----------------
extern "C" void kernel_launch(void* const* d_in, const int* in_sizes, int n_in,
                              void* d_out, int out_size, void* d_ws, size_t ws_size,
                              hipStream_t stream) {
  const float* x     = (const float*)d_in[0];
  const unsigned char* smask = (const unsigned char*)d_in[1];
  const float* pc    = (const float*)d_in[2];
  const float* ec    = (const float*)d_in[3];
  const float* dc    = (const float*)d_in[4];
  const float* pbins = (const float*)d_in[5];
  const float* ebins = (const float*)d_in[6];
  const float* pemb  = (const float*)d_in[7];
  const float* eemb  = (const float*)d_in[8];

  float* out = (float*)d_out;
  float* o_xexp  = out;
  float* o_pit   = out + (size_t)16777216;
  float* o_ene   = o_pit + 16384;
  float* o_ldur  = o_ene + 16384;
  float* o_dur   = o_ldur + 16384;
  float* o_mlen  = o_dur + 16384;
  float* o_mmask = o_mlen + 32;

  const size_t PL = (size_t)MM * HH;       // f16 elems per plane
  f16* p = (f16*)d_ws;
  f16 *XPh = p,        *XPl = p + PL;
  f16 *Tdh = p + 2*PL, *Tdl = p + 3*PL;
  f16 *Tph = p + 4*PL, *Tpl = p + 5*PL;
  f16 *Udh = p + 6*PL, *Udl = p + 7*PL;
  f16 *Uph = p + 8*PL, *Upl = p + 9*PL;
  f16 *X1h = p + 10*PL, *X1l = p + 11*PL;
  f16 *Teh = p + 12*PL, *Tel = p + 13*PL;
  f16 *Ueh = p + 14*PL, *Uel = p + 15*PL;
  f16 *X2h = p + 16*PL, *X2l = p + 17*PL;
  f16* Wt  = p + 18*PL;                    // 6 packed convs of WSZP
  float* pred_d = (float*)(Wt + 6 * WSZP);
  int*   cum = (int*)(pred_d + MM);
  int*   mlw = cum + MM;

  #define WPK(i) (Wt + (size_t)(i) * WSZP)

  // weights: 0=dur w1(9), 1=dur w2(13), 2=pit w1(19), 3=pit w2(23), 4=ene w1(29), 5=ene w2(33)
  wsplit6<<<dim3(192, 6), 256, 0, stream>>>(
      (const float*)d_in[9], (const float*)d_in[13], (const float*)d_in[19],
      (const float*)d_in[23], (const float*)d_in[29], (const float*)d_in[33], Wt);

  split2<<<2048, 256, 0, stream>>>(x, XPh, XPl);

  dim3 cgrid2(128, 2, 2);    // dur+pit fused
  dim3 cgrid1(128, 2, 1);    // energy alone
  dim3 rgrid(MM / 4);
  dim3 rgrid2(MM / 4, 2);

  // fused dur+pit conv1
  convA<<<cgrid2, 256, 0, stream>>>(
      XPh, XPl, XPh, XPl, WPK(0), WPK(2),
      (const float*)d_in[10], (const float*)d_in[20],
      Tdh, Tdl, Tph, Tpl);
  lnF<<<rgrid2, 256, 0, stream>>>(Tdh, Tdl, Tph, Tpl,
      (const float*)d_in[11], (const float*)d_in[12],
      (const float*)d_in[21], (const float*)d_in[22]);
  // fused dur+pit conv2
  convA<<<cgrid2, 256, 0, stream>>>(
      Tdh, Tdl, Tph, Tpl, WPK(1), WPK(3),
      (const float*)d_in[14], (const float*)d_in[24],
      Udh, Udl, Uph, Upl);
  lnheadD<<<rgrid2, 256, 0, stream>>>(
      Udh, Udl, Uph, Upl,
      (const float*)d_in[15], (const float*)d_in[16],
      (const float*)d_in[17], (const float*)d_in[18],
      (const float*)d_in[25], (const float*)d_in[26],
      (const float*)d_in[27], (const float*)d_in[28],
      smask, pc, o_ldur, pred_d, o_pit, pbins, pemb,
      XPh, XPl, X1h, X1l);
  dur_post<<<BB, 512, 0, stream>>>(pred_d, dc, o_dur, o_mlen, cum, mlw);

  // energy conv1 (input X1) -> Te
  convA<<<cgrid1, 256, 0, stream>>>(
      X1h, X1l, X1h, X1l, WPK(4), WPK(4),
      (const float*)d_in[30], (const float*)d_in[30],
      Teh, Tel, Teh, Tel);
  lnF<<<dim3(MM / 4, 1), 256, 0, stream>>>(Teh, Tel, Teh, Tel,
      (const float*)d_in[31], (const float*)d_in[32],
      (const float*)d_in[31], (const float*)d_in[32]);
  // energy conv2 -> Ue
  convA<<<cgrid1, 256, 0, stream>>>(
      Teh, Tel, Teh, Tel, WPK(5), WPK(5),
      (const float*)d_in[34], (const float*)d_in[34],
      Ueh, Uel, Ueh, Uel);
  lnheadE<<<rgrid, 256, 0, stream>>>(Ueh, Uel,
      (const float*)d_in[35], (const float*)d_in[36],
      (const float*)d_in[37], (const float*)d_in[38],
      smask, ec, o_ene, ebins, eemb, X1h, X1l, X2h, X2l);

  dim3 ggrid(MAXMEL / 4, BB);
  gather_planes<<<ggrid, 256, 0, stream>>>(X2h, X2l, cum, mlw, o_xexp, o_mmask);

  #undef WPK
}

// Round 8
// 228.102 us; speedup vs baseline: 1.3227x; 1.3227x over previous
//
#include <hip/hip_runtime.h>
#include <stdint.h>

#define BB 32
#define SS 512
#define HH 256
#define MM (BB*SS)     // 16384 rows
#define MAXMEL 2048

typedef _Float16 f16;
typedef _Float16 f16x4 __attribute__((ext_vector_type(4)));
typedef _Float16 f16x8 __attribute__((ext_vector_type(8)));
typedef float    f32x16 __attribute__((ext_vector_type(16)));

#define BAR()  asm volatile("s_barrier" ::: "memory")
#define VMW9() asm volatile("s_waitcnt vmcnt(9)" ::: "memory")
#define VMW0() asm volatile("s_waitcnt vmcnt(0)" ::: "memory")

// Xg layout: [cb 16][row MM][16 chans] (32B per row per 16-chan panel)
__device__ __forceinline__ size_t xoff(int row, int chan) {
  return ((size_t)(chan >> 4) * MM + row) * 16 + (chan & 15);
}

// LDS map (bytes): B0 @0 (24576 = [p2][tap3][col128][g2][16B]), B1 @24576,
// A0 @49152 (12288 = [p2][lr192][g2][16B], + 64B zero tail), A1 @61504.
#define AOFF  49152
#define ABUF  12352
#define AZ    61440         // A0 zero tail; A1's lands at 73792
#define BBUF  24576
#define LDSSZ 73856
#define WSZP ((size_t)393216)   // packed weight f16 elems per conv (both planes)

// ---------------- conv1d (K=3 SAME, 256->256), split-f16 MFMA ----------------
// Block 128x128, 4 waves (2x2), wave 64x64 as 2x2 frags of 32x32x16.
// 16 steps of (16 chans x 3 taps). Double-buffered LDS, counted vmcnt(9).
// 3-product split: Ahi*Bhi + Ahi*Blo + Alo*Bhi (~f32 accuracy).
// RAW=0: bz=predictor (fused pair). RAW=1: bz=K-half, raw f32 partials.
// LDS reads: consecutive lanes -> 32B-stride 16B granules = 2-way (free, m136).
template<int NS, int RAW>
__global__ __launch_bounds__(256) void conv16(
    const f16* __restrict__ X0h, const f16* __restrict__ X0l,
    const f16* __restrict__ X1h_, const f16* __restrict__ X1l_,
    const f16* __restrict__ W0, const f16* __restrict__ W1,   // packed
    const float* __restrict__ bias0, const float* __restrict__ bias1,
    f16* __restrict__ Y0h, f16* __restrict__ Y0l,
    f16* __restrict__ Y1h, f16* __restrict__ Y1l,
    float* __restrict__ Craw)
{
  __shared__ __align__(16) unsigned char smem[LDSSZ];
  const int tid = threadIdx.x;
  const int lane = tid & 63, wid = tid >> 6;
  const int bm = blockIdx.x, bn = blockIdx.y, bz = blockIdx.z;
  const int l31 = lane & 31, half = lane >> 5;
  const int hx4 = half << 4;
  const int wr = wid >> 1, wc = wid & 1;

  const int s0 = RAW ? bz * 8 : 0;
  const f16* Xh = (RAW || bz == 0) ? X0h : X1h_;
  const f16* Xl = (RAW || bz == 0) ? X0l : X1l_;
  const f16* Wp = (RAW || bz == 0) ? W0 : W1;

  // ---- stage descriptors: 9 DMA per thread (A 12 + B 24 = 36 per block) ----
  const f16* sb[9]; int sdst[9]; int sdb[9]; size_t sstr[9];
  #pragma unroll
  for (int i = 0; i < 9; ++i) {
    int j = wid * 9 + i;
    if (j < 12) {                 // A: 6 segs of 32 rows x 2 planes
      int p = j / 6, seg = j % 6;
      int rowstart = bm * 128 - 32 + seg * 32;
      rowstart = rowstart < 0 ? 0 : (rowstart > MM - 32 ? MM - 32 : rowstart);
      sb[i]   = (p ? Xl : Xh) + (size_t)rowstart * 16 + lane * 8;
      sstr[i] = (size_t)MM * 16;
      sdst[i] = AOFF + p * 6144 + seg * 1024 + lane * 16;
      sdb[i]  = ABUF;
    } else {                      // B: [p][tap][4 x 1KB] per step
      int jj = j - 12;
      int p = jj / 12, rest = jj % 12;
      int tap = rest >> 2, q4 = rest & 3;
      sb[i]   = Wp + (((size_t)(bn * 16) * 2 + p) * 3 + tap) * 2048
                   + q4 * 512 + lane * 8;
      sstr[i] = 12288;
      sdst[i] = p * 12288 + tap * 4096 + q4 * 1024 + lane * 16;
      sdb[i]  = BBUF;
    }
  }

  // ---- fragment read addresses ----
  int a_addr[3][2][2];            // [tap][mi][p]
  #pragma unroll
  for (int tap = 0; tap < 3; ++tap)
    #pragma unroll
    for (int mi = 0; mi < 2; ++mi) {
      int row_l = wr * 64 + mi * 32 + l31;
      int sseq = (bm & 3) * 128 + row_l + tap - 1;
      bool valid = (unsigned)sseq < 512u;
      int lr = row_l + tap + 31;       // local (rowstart-relative) row
      #pragma unroll
      for (int p = 0; p < 2; ++p)
        a_addr[tap][mi][p] = valid ? (AOFF + p * 6144 + lr * 32) : AZ;
    }
  int b_col[2];
  #pragma unroll
  for (int n = 0; n < 2; ++n)
    b_col[n] = (wc * 64 + n * 32 + l31) * 32;

  f32x16 acc[2][2];
  #pragma unroll
  for (int mi = 0; mi < 2; ++mi)
    #pragma unroll
    for (int ni = 0; ni < 2; ++ni) acc[mi][ni] = (f32x16)0.f;

  auto STAGE = [&](int buf, int step) {
    #pragma unroll
    for (int i = 0; i < 9; ++i)
      __builtin_amdgcn_global_load_lds(
        (const __attribute__((address_space(1))) void*)(sb[i] + (size_t)step * sstr[i]),
        (__attribute__((address_space(3))) void*)(smem + sdst[i] + buf * sdb[i]),
        16, 0, 0);
  };

  auto COMP = [&](int buf) {
    #pragma unroll
    for (int tap = 0; tap < 3; ++tap) {
      f16x8 av[2][2], bv[2][2];        // [p][mi], [p][ni]
      #pragma unroll
      for (int p = 0; p < 2; ++p)
        #pragma unroll
        for (int q = 0; q < 2; ++q) {
          av[p][q] = *(const f16x8*)(smem + (a_addr[tap][q][p] + buf * ABUF + hx4));
          bv[p][q] = *(const f16x8*)(smem + (buf * BBUF + p * 12288 + tap * 4096 + b_col[q] + hx4));
        }
      #pragma unroll
      for (int mi = 0; mi < 2; ++mi)
        #pragma unroll
        for (int ni = 0; ni < 2; ++ni) {
          acc[mi][ni] = __builtin_amdgcn_mfma_f32_32x32x16_f16(av[0][mi], bv[0][ni], acc[mi][ni], 0, 0, 0);
          acc[mi][ni] = __builtin_amdgcn_mfma_f32_32x32x16_f16(av[0][mi], bv[1][ni], acc[mi][ni], 0, 0, 0);
          acc[mi][ni] = __builtin_amdgcn_mfma_f32_32x32x16_f16(av[1][mi], bv[0][ni], acc[mi][ni], 0, 0, 0);
        }
    }
  };

  if (tid < 4) {
    *(float4*)(smem + AZ + tid * 16) = make_float4(0.f, 0.f, 0.f, 0.f);
    *(float4*)(smem + AZ + ABUF + tid * 16) = make_float4(0.f, 0.f, 0.f, 0.f);
  }
  STAGE(0, s0); STAGE(1, s0 + 1);
  __syncthreads();                 // drains vmcnt; zeros + first 2 steps visible

  #pragma unroll
  for (int i = 0; i < NS; ++i) {
    COMP(i & 1);
    BAR();                         // all waves done reading buf i&1
    if (i < NS - 2)       { STAGE(i & 1, s0 + i + 2); VMW9(); }
    else if (i == NS - 2) { VMW0(); }
    BAR();                         // step i+1 landed everywhere
  }

  // epilogue. C/D layout: col=lane&31, row=(reg&3)+8*(reg>>2)+4*(lane>>5)
  if constexpr (RAW) {
    float* C = Craw + (size_t)bz * MM * 256;
    #pragma unroll
    for (int mi = 0; mi < 2; ++mi)
      #pragma unroll
      for (int ni = 0; ni < 2; ++ni) {
        int colg = bn * 128 + wc * 64 + ni * 32 + l31;
        #pragma unroll
        for (int r = 0; r < 16; ++r) {
          int rowl = (r & 3) + 8 * (r >> 2) + 4 * half;
          size_t rowg = (size_t)bm * 128 + wr * 64 + mi * 32 + rowl;
          C[rowg * 256 + colg] = acc[mi][ni][r];
        }
      }
  } else {
    const float* bias = bz ? bias1 : bias0;
    f16* Yh = bz ? Y1h : Y0h;
    f16* Yl = bz ? Y1l : Y0l;
    #pragma unroll
    for (int mi = 0; mi < 2; ++mi)
      #pragma unroll
      for (int ni = 0; ni < 2; ++ni) {
        int colg = bn * 128 + wc * 64 + ni * 32 + l31;
        float bvs = bias[colg];
        size_t cbase = (size_t)(colg >> 4) * MM * 16 + (colg & 15);
        #pragma unroll
        for (int r = 0; r < 16; ++r) {
          int rowl = (r & 3) + 8 * (r >> 2) + 4 * half;
          int rowg = bm * 128 + wr * 64 + mi * 32 + rowl;
          float v = fmaxf(acc[mi][ni][r] + bvs, 0.f);
          f16 h = (f16)v;
          f16 l = (f16)(v - (float)h);
          size_t o = cbase + (size_t)rowg * 16;
          Yh[o] = h;
          Yl[o] = l;
        }
      }
  }
}

// ---------------- weight pack+split, all 6 weights in one launch ----------------
// packed per conv: [bn2][s16][p2][tap3][col128][g2][8 f16]; p0=hi, p1=lo
__global__ __launch_bounds__(256) void wsplit6(
    const float* __restrict__ W0, const float* __restrict__ W1,
    const float* __restrict__ W2, const float* __restrict__ W3,
    const float* __restrict__ W4, const float* __restrict__ W5,
    f16* __restrict__ Wt)
{
  int z = blockIdx.y;
  const float* W = z==0?W0 : z==1?W1 : z==2?W2 : z==3?W3 : z==4?W4 : W5;
  f16* T = Wt + (size_t)z * WSZP;
  int id = blockIdx.x * 256 + threadIdx.x;    // [0, 49152) 16B units
  int g = id & 1;
  int t1 = id >> 1;
  int col = t1 & 127;
  int t2 = t1 >> 7;
  int tap = t2 % 3;
  int t3 = t2 / 3;
  int p = t3 & 1;
  int t4 = t3 >> 1;
  int s = t4 & 15;
  int bn = t4 >> 4;
  int chan = s * 16 + g * 8;
  int colg = bn * 128 + col;
  f16x8 o;
  #pragma unroll
  for (int e = 0; e < 8; ++e) {
    float w = W[(size_t)(tap * 256 + chan + e) * 256 + colg];
    f16 h = (f16)w;
    o[e] = p ? (f16)(w - (float)h) : h;
  }
  *(f16x8*)(T + (size_t)id * 8) = o;
}

// ---------------- split f32 -> hi/lo planes (Xg layout) ----------------
__global__ __launch_bounds__(256) void split2(
    const float* __restrict__ X, f16* __restrict__ Hi, f16* __restrict__ Lo)
{
  int id = blockIdx.x * 256 + threadIdx.x;    // [0, MM*32)
  int row = id >> 5, chan = (id & 31) * 8;
  const float* src = X + (size_t)row * 256 + chan;
  float4 v0 = *(const float4*)src;
  float4 v1 = *(const float4*)(src + 4);
  float vv[8] = {v0.x, v0.y, v0.z, v0.w, v1.x, v1.y, v1.z, v1.w};
  f16x8 h, l;
  #pragma unroll
  for (int j = 0; j < 8; ++j) {
    f16 hh = (f16)vv[j];
    h[j] = hh;
    l[j] = (f16)(vv[j] - (float)hh);
  }
  size_t o = xoff(row, chan);
  *(f16x8*)(Hi + o) = h;
  *(f16x8*)(Lo + o) = l;
}

// ---------------- fused LN (z picks predictor set) ----------------
__global__ __launch_bounds__(256) void lnF(
    f16* __restrict__ P0h, f16* __restrict__ P0l,
    f16* __restrict__ P1h, f16* __restrict__ P1l,
    const float* __restrict__ g0, const float* __restrict__ be0,
    const float* __restrict__ g1, const float* __restrict__ be1)
{
  int z = blockIdx.y;
  f16* Ph = z ? P1h : P0h;
  f16* Pl = z ? P1l : P0l;
  const float* g  = z ? g1 : g0;
  const float* be = z ? be1 : be0;
  int row  = blockIdx.x * 4 + (threadIdx.x >> 6);
  int lane = threadIdx.x & 63;
  size_t o = xoff(row, lane * 4);
  f16x4 h = *(const f16x4*)(Ph + o);
  f16x4 l = *(const f16x4*)(Pl + o);
  float v[4];
  #pragma unroll
  for (int j = 0; j < 4; ++j) v[j] = (float)h[j] + (float)l[j];
  float s = v[0] + v[1] + v[2] + v[3];
  float q = v[0]*v[0] + v[1]*v[1] + v[2]*v[2] + v[3]*v[3];
  #pragma unroll
  for (int d = 32; d > 0; d >>= 1) { s += __shfl_xor(s, d); q += __shfl_xor(q, d); }
  float mean = s * (1.f / 256.f);
  float var  = q * (1.f / 256.f) - mean * mean;
  float inv  = 1.0f / sqrtf(var + 1e-5f);
  float4 gg = *(const float4*)(g + lane * 4);
  float4 bb = *(const float4*)(be + lane * 4);
  float gv[4] = {gg.x, gg.y, gg.z, gg.w};
  float bv[4] = {bb.x, bb.y, bb.z, bb.w};
  #pragma unroll
  for (int j = 0; j < 4; ++j) {
    float oo = (v[j] - mean) * inv * gv[j] + bv[j];
    f16 hh = (f16)oo;
    h[j] = hh;
    l[j] = (f16)(oo - (float)hh);
  }
  *(f16x4*)(Ph + o) = h;
  *(f16x4*)(Pl + o) = l;
}

// ------- fused LN+head for dur (z=0) and pit (z=1, + bucket + emb add) -------
__global__ __launch_bounds__(256) void lnheadD(
    const f16* __restrict__ U0h, const f16* __restrict__ U0l,
    const f16* __restrict__ U1h, const f16* __restrict__ U1l,
    const float* __restrict__ g0, const float* __restrict__ be0,
    const float* __restrict__ wl0, const float* __restrict__ bl0,
    const float* __restrict__ g1, const float* __restrict__ be1,
    const float* __restrict__ wl1, const float* __restrict__ bl1,
    const unsigned char* __restrict__ mask, const float* __restrict__ pc,
    float* __restrict__ o_ldur, float* __restrict__ pred_d,
    float* __restrict__ o_pit,
    const float* __restrict__ pbins, const float* __restrict__ pemb,
    const f16* __restrict__ XPh, const f16* __restrict__ XPl,
    f16* __restrict__ X1h, f16* __restrict__ X1l)
{
  int z = blockIdx.y;
  int row  = blockIdx.x * 4 + (threadIdx.x >> 6);
  int lane = threadIdx.x & 63;
  size_t o = xoff(row, lane * 4);
  const f16* Uh = z ? U1h : U0h;
  const f16* Ul = z ? U1l : U0l;
  f16x4 h = *(const f16x4*)(Uh + o);
  f16x4 l = *(const f16x4*)(Ul + o);
  float v[4];
  #pragma unroll
  for (int j = 0; j < 4; ++j) v[j] = (float)h[j] + (float)l[j];
  float s = v[0] + v[1] + v[2] + v[3];
  float q = v[0]*v[0] + v[1]*v[1] + v[2]*v[2] + v[3]*v[3];
  #pragma unroll
  for (int d = 32; d > 0; d >>= 1) { s += __shfl_xor(s, d); q += __shfl_xor(q, d); }
  float mean = s * (1.f / 256.f);
  float var  = q * (1.f / 256.f) - mean * mean;
  float inv  = 1.0f / sqrtf(var + 1e-5f);
  const float* g  = z ? g1  : g0;
  const float* be = z ? be1 : be0;
  const float* wl = z ? wl1 : wl0;
  float4 gg = *(const float4*)(g + lane * 4);
  float4 bb = *(const float4*)(be + lane * 4);
  float4 ww = *(const float4*)(wl + lane * 4);
  float gv[4] = {gg.x, gg.y, gg.z, gg.w};
  float bv[4] = {bb.x, bb.y, bb.z, bb.w};
  float wv[4] = {ww.x, ww.y, ww.z, ww.w};
  float acc = 0.f;
  #pragma unroll
  for (int j = 0; j < 4; ++j)
    acc += ((v[j] - mean) * inv * gv[j] + bv[j]) * wv[j];
  #pragma unroll
  for (int d = 32; d > 0; d >>= 1) acc += __shfl_xor(acc, d);
  float r = acc + (z ? bl1 : bl0)[0];
  if (mask[row]) r = 0.f;
  if (z == 0) {
    if (lane == 0) { o_ldur[row] = r; pred_d[row] = r; }
  } else {
    r *= pc[0];
    if (lane == 0) o_pit[row] = r;
    int lo = 0, hi = 255;
    while (lo < hi) { int mid = (lo + hi) >> 1; if (pbins[mid] < r) lo = mid + 1; else hi = mid; }
    f16x4 xh = *(const f16x4*)(XPh + o);
    f16x4 xl = *(const f16x4*)(XPl + o);
    float4 e = *(const float4*)(pemb + (size_t)lo * HH + lane * 4);
    float ev[4] = {e.x, e.y, e.z, e.w};
    #pragma unroll
    for (int j = 0; j < 4; ++j) {
      float oo = (float)xh[j] + (float)xl[j] + ev[j];
      f16 hh = (f16)oo;
      xh[j] = hh;
      xl[j] = (f16)(oo - (float)hh);
    }
    *(f16x4*)(X1h + o) = xh;
    *(f16x4*)(X1l + o) = xl;
  }
}

// ------- energy: sum split-K partials + bias + relu + LN -> planes -------
__global__ __launch_bounds__(256) void lnS(
    const float* __restrict__ C0, const float* __restrict__ C1,
    const float* __restrict__ bias,
    const float* __restrict__ g, const float* __restrict__ be,
    f16* __restrict__ Yh, f16* __restrict__ Yl)
{
  int row  = blockIdx.x * 4 + (threadIdx.x >> 6);
  int lane = threadIdx.x & 63;
  size_t ci = (size_t)row * 256 + lane * 4;
  float4 a = *(const float4*)(C0 + ci);
  float4 b = *(const float4*)(C1 + ci);
  float4 bs = *(const float4*)(bias + lane * 4);
  float v[4] = {fmaxf(a.x + b.x + bs.x, 0.f), fmaxf(a.y + b.y + bs.y, 0.f),
                fmaxf(a.z + b.z + bs.z, 0.f), fmaxf(a.w + b.w + bs.w, 0.f)};
  float s = v[0] + v[1] + v[2] + v[3];
  float q = v[0]*v[0] + v[1]*v[1] + v[2]*v[2] + v[3]*v[3];
  #pragma unroll
  for (int d = 32; d > 0; d >>= 1) { s += __shfl_xor(s, d); q += __shfl_xor(q, d); }
  float mean = s * (1.f / 256.f);
  float var  = q * (1.f / 256.f) - mean * mean;
  float inv  = 1.0f / sqrtf(var + 1e-5f);
  float4 gg = *(const float4*)(g + lane * 4);
  float4 bb = *(const float4*)(be + lane * 4);
  float gv[4] = {gg.x, gg.y, gg.z, gg.w};
  float bv[4] = {bb.x, bb.y, bb.z, bb.w};
  f16x4 h, l;
  #pragma unroll
  for (int j = 0; j < 4; ++j) {
    float oo = (v[j] - mean) * inv * gv[j] + bv[j];
    f16 hh = (f16)oo;
    h[j] = hh;
    l[j] = (f16)(oo - (float)hh);
  }
  size_t o = xoff(row, lane * 4);
  *(f16x4*)(Yh + o) = h;
  *(f16x4*)(Yl + o) = l;
}

// ------- energy final: sum partials + bias + relu + LN + head + bucket -------
__global__ __launch_bounds__(256) void lnheadS(
    const float* __restrict__ C0, const float* __restrict__ C1,
    const float* __restrict__ bias,
    const float* __restrict__ g, const float* __restrict__ be,
    const float* __restrict__ wl, const float* __restrict__ bl,
    const unsigned char* __restrict__ mask, const float* __restrict__ ec,
    float* __restrict__ o_ene,
    const float* __restrict__ ebins, const float* __restrict__ eemb,
    const f16* __restrict__ X1h, const f16* __restrict__ X1l,
    f16* __restrict__ X2h, f16* __restrict__ X2l)
{
  int row  = blockIdx.x * 4 + (threadIdx.x >> 6);
  int lane = threadIdx.x & 63;
  size_t ci = (size_t)row * 256 + lane * 4;
  float4 a = *(const float4*)(C0 + ci);
  float4 b = *(const float4*)(C1 + ci);
  float4 bs = *(const float4*)(bias + lane * 4);
  float v[4] = {fmaxf(a.x + b.x + bs.x, 0.f), fmaxf(a.y + b.y + bs.y, 0.f),
                fmaxf(a.z + b.z + bs.z, 0.f), fmaxf(a.w + b.w + bs.w, 0.f)};
  float s = v[0] + v[1] + v[2] + v[3];
  float q = v[0]*v[0] + v[1]*v[1] + v[2]*v[2] + v[3]*v[3];
  #pragma unroll
  for (int d = 32; d > 0; d >>= 1) { s += __shfl_xor(s, d); q += __shfl_xor(q, d); }
  float mean = s * (1.f / 256.f);
  float var  = q * (1.f / 256.f) - mean * mean;
  float inv  = 1.0f / sqrtf(var + 1e-5f);
  float4 gg = *(const float4*)(g + lane * 4);
  float4 bb = *(const float4*)(be + lane * 4);
  float4 ww = *(const float4*)(wl + lane * 4);
  float gv[4] = {gg.x, gg.y, gg.z, gg.w};
  float bv[4] = {bb.x, bb.y, bb.z, bb.w};
  float wv[4] = {ww.x, ww.y, ww.z, ww.w};
  float acc = 0.f;
  #pragma unroll
  for (int j = 0; j < 4; ++j)
    acc += ((v[j] - mean) * inv * gv[j] + bv[j]) * wv[j];
  #pragma unroll
  for (int d = 32; d > 0; d >>= 1) acc += __shfl_xor(acc, d);
  float r = acc + bl[0];
  if (mask[row]) r = 0.f;
  r *= ec[0];
  if (lane == 0) o_ene[row] = r;
  int lo = 0, hi = 255;
  while (lo < hi) { int mid = (lo + hi) >> 1; if (ebins[mid] < r) lo = mid + 1; else hi = mid; }
  size_t o = xoff(row, lane * 4);
  f16x4 xh = *(const f16x4*)(X1h + o);
  f16x4 xl = *(const f16x4*)(X1l + o);
  float4 e = *(const float4*)(eemb + (size_t)lo * HH + lane * 4);
  float ev[4] = {e.x, e.y, e.z, e.w};
  #pragma unroll
  for (int j = 0; j < 4; ++j) {
    float oo = (float)xh[j] + (float)xl[j] + ev[j];
    f16 hh = (f16)oo;
    xh[j] = hh;
    xl[j] = (f16)(oo - (float)hh);
  }
  *(f16x4*)(X2h + o) = xh;
  *(f16x4*)(X2l + o) = xl;
}

// ---------------- duration post: dur, cumsum, mel_len ----------------
__global__ __launch_bounds__(512) void dur_post(
    const float* __restrict__ logdur, const float* __restrict__ dc,
    float* __restrict__ out_dur, float* __restrict__ out_mel_len,
    int* __restrict__ cum_ws, int* __restrict__ mel_len_ws)
{
  __shared__ int wsum[8];
  int b = blockIdx.x, t = threadIdx.x;
  float ld = logdur[b * SS + t];
  float d  = fmaxf(rintf(expf(ld) - 1.f) * dc[0], 0.f);
  out_dur[b * SS + t] = d;
  int di = (int)d;
  int lane = t & 63, w = t >> 6;
  int x = di;
  #pragma unroll
  for (int dd = 1; dd < 64; dd <<= 1) {
    int n = __shfl_up(x, dd);
    if (lane >= dd) x += n;
  }
  if (lane == 63) wsum[w] = x;
  __syncthreads();
  int off = 0;
  for (int i = 0; i < w; ++i) off += wsum[i];
  x += off;
  cum_ws[b * SS + t] = x;
  if (t == SS - 1) {
    int ml = min(x, MAXMEL);
    mel_len_ws[b] = ml;
    out_mel_len[b] = (float)ml;
  }
}

// ---------------- length regulator from Xg planes ----------------
__global__ __launch_bounds__(256) void gather_planes(
    const f16* __restrict__ Xhi, const f16* __restrict__ Xlo,
    const int* __restrict__ cum, const int* __restrict__ mel_len_ws,
    float* __restrict__ out_x, float* __restrict__ out_mask)
{
  __shared__ int c[SS];
  int b   = blockIdx.y;
  int tid = threadIdx.x;
  c[tid]       = cum[b * SS + tid];
  c[tid + 256] = cum[b * SS + tid + 256];
  __syncthreads();
  int w = tid >> 6, lane = tid & 63;
  int t = blockIdx.x * 4 + w;
  int lo = 0, hi = SS;
  while (lo < hi) { int mid = (lo + hi) >> 1; if (c[mid] <= t) lo = mid + 1; else hi = mid; }
  int idx = min(lo, SS - 1);
  int ml  = mel_len_ws[b];
  bool m  = (t >= ml);
  float4 v = make_float4(0.f, 0.f, 0.f, 0.f);
  if (!m) {
    size_t o = xoff(b * SS + idx, lane * 4);
    f16x4 xh = *(const f16x4*)(Xhi + o);
    f16x4 xl = *(const f16x4*)(Xlo + o);
    v.x = (float)xh[0] + (float)xl[0];
    v.y = (float)xh[1] + (float)xl[1];
    v.z = (float)xh[2] + (float)xl[2];
    v.w = (float)xh[3] + (float)xl[3];
  }
  *(float4*)(out_x + ((size_t)b * MAXMEL + t) * HH + lane * 4) = v;
  if (lane == 0) out_mask[b * MAXMEL + t] = m ? 1.f : 0.f;
}

// ---------------- launcher ----------------
extern "C" void kernel_launch(void* const* d_in, const int* in_sizes, int n_in,
                              void* d_out, int out_size, void* d_ws, size_t ws_size,
                              hipStream_t stream) {
  const float* x     = (const float*)d_in[0];
  const unsigned char* smask = (const unsigned char*)d_in[1];
  const float* pc    = (const float*)d_in[2];
  const float* ec    = (const float*)d_in[3];
  const float* dc    = (const float*)d_in[4];
  const float* pbins = (const float*)d_in[5];
  const float* ebins = (const float*)d_in[6];
  const float* pemb  = (const float*)d_in[7];
  const float* eemb  = (const float*)d_in[8];

  float* out = (float*)d_out;
  float* o_xexp  = out;
  float* o_pit   = out + (size_t)16777216;
  float* o_ene   = o_pit + 16384;
  float* o_ldur  = o_ene + 16384;
  float* o_dur   = o_ldur + 16384;
  float* o_mlen  = o_dur + 16384;
  float* o_mmask = o_mlen + 32;

  const size_t PL = (size_t)MM * HH;       // f16 elems per plane
  f16* p = (f16*)d_ws;
  f16 *XPh = p,        *XPl = p + PL;
  f16 *Tdh = p + 2*PL, *Tdl = p + 3*PL;
  f16 *Tph = p + 4*PL, *Tpl = p + 5*PL;
  f16 *Udh = p + 6*PL, *Udl = p + 7*PL;
  f16 *Uph = p + 8*PL, *Upl = p + 9*PL;
  f16 *X1h = p + 10*PL, *X1l = p + 11*PL;
  f16 *Teh = p + 12*PL, *Tel = p + 13*PL;
  f16 *X2h = p + 14*PL, *X2l = p + 15*PL;
  f16* Wt  = p + 16*PL;                    // 6 packed convs of WSZP
  float* C0 = (float*)(Wt + 6 * WSZP);     // 2 x MM*256 f32
  float* C1 = C0 + (size_t)MM * 256;
  float* pred_d = C1 + (size_t)MM * 256;
  int*   cum = (int*)(pred_d + MM);
  int*   mlw = cum + MM;

  #define WPK(i) (Wt + (size_t)(i) * WSZP)

  // weights: 0=dur w1(9), 1=dur w2(13), 2=pit w1(19), 3=pit w2(23), 4=ene w1(29), 5=ene w2(33)
  wsplit6<<<dim3(192, 6), 256, 0, stream>>>(
      (const float*)d_in[9], (const float*)d_in[13], (const float*)d_in[19],
      (const float*)d_in[23], (const float*)d_in[29], (const float*)d_in[33], Wt);

  split2<<<2048, 256, 0, stream>>>(x, XPh, XPl);

  dim3 cgrid(128, 2, 2);
  dim3 rgrid(MM / 4);
  dim3 rgrid2(MM / 4, 2);

  // fused dur+pit conv1
  conv16<16, 0><<<cgrid, 256, 0, stream>>>(
      XPh, XPl, XPh, XPl, WPK(0), WPK(2),
      (const float*)d_in[10], (const float*)d_in[20],
      Tdh, Tdl, Tph, Tpl, nullptr);
  lnF<<<rgrid2, 256, 0, stream>>>(Tdh, Tdl, Tph, Tpl,
      (const float*)d_in[11], (const float*)d_in[12],
      (const float*)d_in[21], (const float*)d_in[22]);
  // fused dur+pit conv2
  conv16<16, 0><<<cgrid, 256, 0, stream>>>(
      Tdh, Tdl, Tph, Tpl, WPK(1), WPK(3),
      (const float*)d_in[14], (const float*)d_in[24],
      Udh, Udl, Uph, Upl, nullptr);
  lnheadD<<<rgrid2, 256, 0, stream>>>(
      Udh, Udl, Uph, Upl,
      (const float*)d_in[15], (const float*)d_in[16],
      (const float*)d_in[17], (const float*)d_in[18],
      (const float*)d_in[25], (const float*)d_in[26],
      (const float*)d_in[27], (const float*)d_in[28],
      smask, pc, o_ldur, pred_d, o_pit, pbins, pemb,
      XPh, XPl, X1h, X1l);
  dur_post<<<BB, 512, 0, stream>>>(pred_d, dc, o_dur, o_mlen, cum, mlw);

  // energy conv1 (split-K over bz) -> raw C
  conv16<8, 1><<<cgrid, 256, 0, stream>>>(
      X1h, X1l, X1h, X1l, WPK(4), WPK(4),
      nullptr, nullptr, nullptr, nullptr, nullptr, nullptr, C0);
  lnS<<<rgrid, 256, 0, stream>>>(C0, C1, (const float*)d_in[30],
      (const float*)d_in[31], (const float*)d_in[32], Teh, Tel);
  // energy conv2 (split-K) -> raw C
  conv16<8, 1><<<cgrid, 256, 0, stream>>>(
      Teh, Tel, Teh, Tel, WPK(5), WPK(5),
      nullptr, nullptr, nullptr, nullptr, nullptr, nullptr, C0);
  lnheadS<<<rgrid, 256, 0, stream>>>(C0, C1, (const float*)d_in[34],
      (const float*)d_in[35], (const float*)d_in[36],
      (const float*)d_in[37], (const float*)d_in[38],
      smask, ec, o_ene, ebins, eemb, X1h, X1l, X2h, X2l);

  dim3 ggrid(MAXMEL / 4, BB);
  gather_planes<<<ggrid, 256, 0, stream>>>(X2h, X2l, cum, mlw, o_xexp, o_mmask);

  #undef WPK
}